// Round 4
// baseline (599.286 us; speedup 1.0000x reference)
//
#include <hip/hip_runtime.h>
#include <hip/hip_bf16.h>

typedef __bf16 bf16;
typedef __bf16 bf16x8 __attribute__((ext_vector_type(8)));
typedef float f32x4 __attribute__((ext_vector_type(4)));

#define L_SZ 200
#define D_SZ 256
#define NROWS (2048 * 200)
#define MB 128           // rows per block in old-path kernels
#define MB2 64           // rows per block in k1f / kpre_k0
#define AST 264          // LDS activation row stride (bf16 elems)
#define N_ATTR 50000
#define NPB ((N_ATTR + MB - 1) / MB)      // old-path P blocks
#define NPB64 ((N_ATTR + MB2 - 1) / MB2)  // 782 P blocks (new path)
#define NK0 (2048 / MB2)                  // 32 h1pre blocks

// ---- ws layout (byte offsets) ----
#define WS_W2F 0u             // w2   swizzled 256x256 -> 131072
#define WS_A1L 131072u        // att1[:, :256] -> 131072
#define WS_A1H 262144u        // att1[:, 256:] -> 131072
#define WS_A2F 393216u        // att2 256x256 -> 131072
#define WS_W1A 524288u        // w1[:, :256] swizzled (KT=8) -> 131072
#define WS_W1F 655360u        // w1 full swizzled (KT=16) -> 262144 (old/fallback)
#define WS_R   917504u        // R[5][256] fp32 -> 5120 (pad 8192)
#define WS_H1P 925696u        // h1pre fp32 [2048][256] -> 2097152
#define WS_SCR 3022848u       // scores fp32 [409600] -> 1638400 (old path)
#define WS_O   4661248u       // old path: o bf16 [409600][256]
#define WS_PART 4661248u      // new path: partials f32 [6400][2][256] -> 13107200
#define WS_STAT 17768448u     // new path: stats f32 [6400][4] -> 102400
#define WS_P   214376448u     // P bf16 [50000][256] -> 25600000
#define WS_NEED_OLD 214376448u
#define WS_NEED_NEW 239976448u

// ---------------- bf16 pack helpers ----------------
__device__ __forceinline__ unsigned pack2(float a, float b) {
    unsigned short ua = __builtin_bit_cast(unsigned short, (bf16)a);
    unsigned short ub = __builtin_bit_cast(unsigned short, (bf16)b);
    return (unsigned)ua | ((unsigned)ub << 16);
}
__device__ __forceinline__ float unpk(unsigned v, int hi) {
    unsigned short u = hi ? (unsigned short)(v >> 16) : (unsigned short)(v & 0xffff);
    return (float)__builtin_bit_cast(bf16, u);
}

// ---------------- weight pre-swizzle (fp32 -> bf16 MFMA B-fragments) ----------------
__device__ __forceinline__ void swz_one(const float* __restrict__ W, bf16* __restrict__ dst,
                                        int KT, int ldw, int koff, int g) {
    int lane = g & 63;
    int kt = (g >> 6) % KT;
    int nt = g / (64 * KT);
    int n = nt * 16 + (lane & 15);
    int k = kt * 32 + (lane >> 4) * 8;
    const float* src = W + (long)n * ldw + koff + k;
    f32x4 a = *(const f32x4*)src;
    f32x4 b = *(const f32x4*)(src + 4);
    bf16x8 v;
    v[0] = (bf16)a[0]; v[1] = (bf16)a[1]; v[2] = (bf16)a[2]; v[3] = (bf16)a[3];
    v[4] = (bf16)b[0]; v[5] = (bf16)b[1]; v[6] = (bf16)b[2]; v[7] = (bf16)b[3];
    *(bf16x8*)(dst + (long)g * 8) = v;
}

__global__ void swizzle_kernel(const float* __restrict__ W, bf16* __restrict__ dst,
                               int KT, int ldw, int koff, int total) {
    int g = blockIdx.x * blockDim.x + threadIdx.x;
    if (g >= total) return;
    swz_one(W, dst, KT, ldw, koff, g);
}

// all 5 new-path swizzles (KT=8, 8192 frags each) + R precompute in one launch.
__global__ void swizzle_all(const float* __restrict__ w2, const float* __restrict__ a1w,
                            const float* __restrict__ a2w, const float* __restrict__ w1,
                            bf16* __restrict__ wf_w2, bf16* __restrict__ wf_a1l,
                            bf16* __restrict__ wf_a2f, bf16* __restrict__ wf_a1h,
                            bf16* __restrict__ wf_w1a,
                            const float* __restrict__ r2e, const float* __restrict__ b1w,
                            float* __restrict__ Rg) {
    __shared__ float e[5 * D_SZ];
    const int blk = blockIdx.x, t = threadIdx.x;
    if (blk == 160) {
        // R[r][n] = b1[n] + w1[n][256:] . r2e[r]  (fp32 exact)
        for (int i = t; i < 5 * D_SZ; i += 256) e[i] = r2e[i];
        __syncthreads();
        const float* wr = w1 + (long)t * 512 + 256;
        float bb = b1w[t];
        for (int r = 0; r < 5; ++r) {
            float a = bb;
            const float* er = e + r * D_SZ;
#pragma unroll
            for (int k = 0; k < D_SZ; k += 4) {
                f32x4 wv = *(const f32x4*)(wr + k);
                a += er[k] * wv[0] + er[k + 1] * wv[1] + er[k + 2] * wv[2] + er[k + 3] * wv[3];
            }
            Rg[r * D_SZ + t] = a;
        }
        return;
    }
    int job = blk >> 5, lb = blk & 31;
    int g = lb * 256 + t;
    const float* W; bf16* dst; int ldw, koff;
    switch (job) {
        case 0:  W = w2;  dst = wf_w2;  ldw = 256; koff = 0;   break;
        case 1:  W = a1w; dst = wf_a1l; ldw = 512; koff = 0;   break;
        case 2:  W = a2w; dst = wf_a2f; ldw = 256; koff = 0;   break;
        case 3:  W = a1w; dst = wf_a1h; ldw = 512; koff = 256; break;
        default: W = w1;  dst = wf_w1a; ldw = 512; koff = 0;   break;
    }
    swz_one(W, dst, 8, ldw, koff, g);
}

// ---------------- shared device helpers ----------------
__device__ __forceinline__ void stage_rows(const int* __restrict__ idxl,
                                           const float* __restrict__ table,
                                           bf16* __restrict__ buf, int t) {
#pragma unroll
    for (int it = 0; it < 16; ++it) {
        int g = it * 256 + t;
        int r = g >> 5;          // 0..127
        int c = g & 31;          // 8-float chunk
        long row = idxl[r];
        const float* f = table + row * D_SZ + c * 8;
        f32x4 a = *(const f32x4*)f;
        f32x4 b = *(const f32x4*)(f + 4);
        bf16x8 v;
        v[0] = (bf16)a[0]; v[1] = (bf16)a[1]; v[2] = (bf16)a[2]; v[3] = (bf16)a[3];
        v[4] = (bf16)b[0]; v[5] = (bf16)b[1]; v[6] = (bf16)b[2]; v[7] = (bf16)b[3];
        *(bf16x8*)(buf + r * AST + c * 8) = v;
    }
}

template <int MT, int KTOT>
__device__ __forceinline__ void gemm_t(const bf16* __restrict__ abase,
                                       const bf16* __restrict__ wfrag, int koff_t,
                                       int wave, int lane, int l16, int quad,
                                       f32x4 (&acc)[MT][4]) {
    const bf16* wbase = wfrag + ((long)(wave * 4) * KTOT + koff_t) * 512 + lane * 8;
    bf16x8 bc[4], bn[4];
#pragma unroll
    for (int nt = 0; nt < 4; ++nt)
        bc[nt] = *(const bf16x8*)(wbase + (long)nt * KTOT * 512);
#pragma unroll
    for (int kt = 0; kt < 8; ++kt) {
        if (kt < 7) {
#pragma unroll
            for (int nt = 0; nt < 4; ++nt)
                bn[nt] = *(const bf16x8*)(wbase + ((long)nt * KTOT + kt + 1) * 512);
        }
        bf16x8 a[MT];
#pragma unroll
        for (int mt = 0; mt < MT; ++mt)
            a[mt] = *(const bf16x8*)(abase + (mt * 16 + l16) * AST + kt * 32 + quad * 8);
#pragma unroll
        for (int nt = 0; nt < 4; ++nt)
#pragma unroll
            for (int mt = 0; mt < MT; ++mt)
                acc[mt][nt] = __builtin_amdgcn_mfma_f32_16x16x32_bf16(a[mt], bc[nt], acc[mt][nt], 0, 0, 0);
#pragma unroll
        for (int nt = 0; nt < 4; ++nt) bc[nt] = bn[nt];
    }
}

template <int MT>
__device__ __forceinline__ void zero_t(f32x4 (&acc)[MT][4]) {
    f32x4 z = {0.f, 0.f, 0.f, 0.f};
#pragma unroll
    for (int mt = 0; mt < MT; ++mt)
#pragma unroll
        for (int nt = 0; nt < 4; ++nt) acc[mt][nt] = z;
}

template <int MT>
__device__ __forceinline__ void store_act_t(bf16* __restrict__ buf, f32x4 (&acc)[MT][4],
                                            const float* bias, int wave, int l16, int quad) {
#pragma unroll
    for (int mt = 0; mt < MT; ++mt)
#pragma unroll
        for (int nt = 0; nt < 4; ++nt) {
            int col = (wave * 4 + nt) * 16 + l16;
#pragma unroll
            for (int r = 0; r < 4; ++r) {
                int row = mt * 16 + quad * 4 + r;
                float v = acc[mt][nt][r] + bias[nt];
                v = v > 0.f ? v : 0.f;
                buf[row * AST + col] = (bf16)v;
            }
        }
}

// store o with bias+relu to LDS AND keep packed bf16 copy in registers
__device__ __forceinline__ void store_act_pack4(bf16* __restrict__ buf, f32x4 (&acc)[4][4],
                                                const float* bias, unsigned (&obak)[4][4][2],
                                                int wave, int l16, int quad) {
#pragma unroll
    for (int mt = 0; mt < 4; ++mt)
#pragma unroll
        for (int nt = 0; nt < 4; ++nt) {
            int col = (wave * 4 + nt) * 16 + l16;
            float v[4];
#pragma unroll
            for (int r = 0; r < 4; ++r) {
                float x = acc[mt][nt][r] + bias[nt];
                v[r] = x > 0.f ? x : 0.f;
                int row = mt * 16 + quad * 4 + r;
                buf[row * AST + col] = (bf16)v[r];
            }
            obak[mt][nt][0] = pack2(v[0], v[1]);
            obak[mt][nt][1] = pack2(v[2], v[3]);
        }
}

template <int MT>
__device__ __forceinline__ void store_lin_t(bf16* __restrict__ buf, f32x4 (&acc)[MT][4],
                                            int wave, int l16, int quad) {
#pragma unroll
    for (int mt = 0; mt < MT; ++mt)
#pragma unroll
        for (int nt = 0; nt < 4; ++nt) {
            int col = (wave * 4 + nt) * 16 + l16;
#pragma unroll
            for (int r = 0; r < 4; ++r) {
                int row = mt * 16 + quad * 4 + r;
                buf[row * AST + col] = (bf16)acc[mt][nt][r];
            }
        }
}

// ---------------- Kpre+K0 (new path, 64-row tiles, 4 blocks/CU) ----------------
// blocks [0, NPB64): P[a] = attr[a] . W1a^T ; blocks [NPB64, NPB64+NK0): h1pre
__launch_bounds__(256, 4)
__global__ void kpre_k0(const float* __restrict__ attr, const bf16* __restrict__ wf_w1a,
                        bf16* __restrict__ Pt,
                        const int* __restrict__ nodes, const float* __restrict__ u2e,
                        const bf16* __restrict__ wf_a1h, const float* __restrict__ a1b,
                        float* __restrict__ h1p) {
    __shared__ __align__(16) bf16 abuf[MB2 * AST];
    const int blk = blockIdx.x, t = threadIdx.x;
    const int wave = t >> 6, lane = t & 63, l16 = t & 15, quad = (t & 63) >> 4;
    const bool isP = blk < NPB64;
    const int blk0 = blk - NPB64;
    const float* table = isP ? attr : u2e;
    // stage 64 fp32 rows -> bf16 LDS
#pragma unroll
    for (int it = 0; it < 8; ++it) {
        int g = it * 256 + t;
        int r = g >> 5, c = g & 31;
        long row;
        if (isP) { row = (long)blk * MB2 + r; if (row >= N_ATTR) row = N_ATTR - 1; }
        else row = nodes[blk0 * MB2 + r];
        const float* f = table + row * D_SZ + c * 8;
        f32x4 a = *(const f32x4*)f;
        f32x4 b = *(const f32x4*)(f + 4);
        bf16x8 v;
        v[0] = (bf16)a[0]; v[1] = (bf16)a[1]; v[2] = (bf16)a[2]; v[3] = (bf16)a[3];
        v[4] = (bf16)b[0]; v[5] = (bf16)b[1]; v[6] = (bf16)b[2]; v[7] = (bf16)b[3];
        *(bf16x8*)(abuf + r * AST + c * 8) = v;
    }
    __syncthreads();
    f32x4 acc[4][4];
    zero_t<4>(acc);
    gemm_t<4, 8>(abuf, isP ? wf_w1a : wf_a1h, 0, wave, lane, l16, quad, acc);
    if (isP) {
        __syncthreads();
        store_lin_t<4>(abuf, acc, wave, l16, quad);
        __syncthreads();
#pragma unroll
        for (int it = 0; it < 8; ++it) {
            int g = it * 256 + t;
            int r = g >> 5, c = g & 31;
            long row = (long)blk * MB2 + r;
            if (row < N_ATTR)
                *(bf16x8*)(Pt + row * D_SZ + c * 8) = *(const bf16x8*)(abuf + r * AST + c * 8);
        }
    } else {
#pragma unroll
        for (int nt = 0; nt < 4; ++nt) {
            int col = (wave * 4 + nt) * 16 + l16;
            float ab = a1b[col];
#pragma unroll
            for (int mt = 0; mt < 4; ++mt)
#pragma unroll
                for (int r = 0; r < 4; ++r) {
                    int row = mt * 16 + quad * 4 + r;
                    h1p[(long)(blk0 * MB2 + row) * D_SZ + col] = acc[mt][nt][r] + ab;
                }
        }
    }
}

// ---------------- K1F: gather->x->o(regs+LDS)->h1->h2->score->segment softmax+reduce
// launch_bounds(256,3): VGPR cap 170. 64 arch + 64 acc + 32 obak = 160 fits ->
// obak stays in registers (at (256,4)/cap-128 it spilled to scratch: R3's +420MB traffic).
__launch_bounds__(256, 3)
__global__ void k1f_fused(const int* __restrict__ hua, const int* __restrict__ hr,
                          const bf16* __restrict__ Pt, const float* __restrict__ Rg,
                          const bf16* __restrict__ wf_w2, const bf16* __restrict__ wf_a1l,
                          const bf16* __restrict__ wf_a2f, const float* __restrict__ h1p,
                          const float* __restrict__ b2w, const float* __restrict__ a2b,
                          const float* __restrict__ a3w,
                          float* __restrict__ parts, float* __restrict__ stats) {
    __shared__ __align__(16) bf16 abuf[MB2 * AST];     // 33792 B
    __shared__ int idx_ua[MB2], idx_r[MB2];            // 512 B
    __shared__ float spart[4][MB2];                    // 1024 B
    __shared__ float wLA[MB2], wLB[MB2];               // 512 B -> ~35.9 KB
    const int blk = blockIdx.x, t = threadIdx.x;
    const int wave = t >> 6, lane = t & 63, l16 = t & 15, quad = (t & 63) >> 4;
    const long r0 = (long)blk * MB2;
    const int b0 = (int)(r0 / L_SZ);
    const int b1i = min(b0 + 1, 2047);
    const long bsplit = (long)(b0 + 1) * L_SZ;
    if (t < MB2) { idx_ua[t] = hua[r0 + t]; idx_r[t] = hr[r0 + t]; }
    __syncthreads();
    // stage x = relu(P[hua] + R[hr]) into abuf  (layer1 is a gather + add; R via L1)
#pragma unroll
    for (int it = 0; it < 4; ++it) {
        int g = it * 256 + t;
        int r = g >> 4, c = g & 15;          // 16 lanes per row, 32B chunks
        long row = idx_ua[r];
        const bf16* pp = Pt + row * D_SZ + c * 16;
        bf16x8 v0 = *(const bf16x8*)pp;
        bf16x8 v1 = *(const bf16x8*)(pp + 8);
        const float* Rr = Rg + idx_r[r] * D_SZ + c * 16;
        f32x4 ra = *(const f32x4*)(Rr);
        f32x4 rb = *(const f32x4*)(Rr + 4);
        f32x4 rc = *(const f32x4*)(Rr + 8);
        f32x4 rd = *(const f32x4*)(Rr + 12);
        bf16x8 o0, o1;
#pragma unroll
        for (int j = 0; j < 4; ++j) {
            float a = (float)v0[j] + ra[j];
            float b = (float)v0[j + 4] + rb[j];
            float cc = (float)v1[j] + rc[j];
            float d = (float)v1[j + 4] + rd[j];
            o0[j]     = (bf16)(a > 0.f ? a : 0.f);
            o0[j + 4] = (bf16)(b > 0.f ? b : 0.f);
            o1[j]     = (bf16)(cc > 0.f ? cc : 0.f);
            o1[j + 4] = (bf16)(d > 0.f ? d : 0.f);
        }
        *(bf16x8*)(abuf + r * AST + c * 16) = o0;
        *(bf16x8*)(abuf + r * AST + c * 16 + 8) = o1;
    }
    __syncthreads();

    f32x4 acc[4][4];
    unsigned obak[4][4][2];
    zero_t<4>(acc);
    gemm_t<4, 8>(abuf, wf_w2, 0, wave, lane, l16, quad, acc);   // layer2
    __syncthreads();                                            // all reads of x done
    float bias2[4];
#pragma unroll
    for (int nt = 0; nt < 4; ++nt) bias2[nt] = b2w[(wave * 4 + nt) * 16 + l16];
    store_act_pack4(abuf, acc, bias2, obak, wave, l16, quad);   // o -> abuf + regs
    __syncthreads();
    zero_t<4>(acc);
    gemm_t<4, 8>(abuf, wf_a1l, 0, wave, lane, l16, quad, acc);  // layer3 (low half)
    __syncthreads();                                            // all reads of o done
    // h1 = relu(acc + h1pre[b(row)][col]) -> abuf  (h1p direct, L2-hit)
    float h0v[4], h1v[4];
#pragma unroll
    for (int nt = 0; nt < 4; ++nt) {
        int col = (wave * 4 + nt) * 16 + l16;
        h0v[nt] = h1p[(long)b0 * D_SZ + col];
        h1v[nt] = h1p[(long)b1i * D_SZ + col];
    }
#pragma unroll
    for (int nt = 0; nt < 4; ++nt) {
        int col = (wave * 4 + nt) * 16 + l16;
#pragma unroll
        for (int mt = 0; mt < 4; ++mt)
#pragma unroll
            for (int r = 0; r < 4; ++r) {
                int row = mt * 16 + quad * 4 + r;
                float bias = ((r0 + row) >= bsplit) ? h1v[nt] : h0v[nt];
                float v = acc[mt][nt][r] + bias;
                v = v > 0.f ? v : 0.f;
                abuf[row * AST + col] = (bf16)v;
            }
    }
    __syncthreads();
    zero_t<4>(acc);
    gemm_t<4, 8>(abuf, wf_a2f, 0, wave, lane, l16, quad, acc);  // layer4

    float bias4[4], a3[4];
#pragma unroll
    for (int nt = 0; nt < 4; ++nt) {
        int col = (wave * 4 + nt) * 16 + l16;
        bias4[nt] = a2b[col];
        a3[nt] = a3w[col];
    }
    float p[4][4];
#pragma unroll
    for (int mt = 0; mt < 4; ++mt)
#pragma unroll
        for (int r = 0; r < 4; ++r) {
            float s = 0.f;
#pragma unroll
            for (int nt = 0; nt < 4; ++nt) {
                float h = acc[mt][nt][r] + bias4[nt];
                h = h > 0.f ? h : 0.f;
                s += h * a3[nt];
            }
            p[mt][r] = s;
        }
#pragma unroll
    for (int off = 1; off < 16; off <<= 1)
#pragma unroll
        for (int mt = 0; mt < 4; ++mt)
#pragma unroll
            for (int r = 0; r < 4; ++r) p[mt][r] += __shfl_xor(p[mt][r], off, 16);
    if (l16 == 0) {
#pragma unroll
        for (int mt = 0; mt < 4; ++mt)
#pragma unroll
            for (int r = 0; r < 4; ++r)
                spart[wave][mt * 16 + quad * 4 + r] = p[mt][r];
    }
    __syncthreads();
    // segment-wise softmax weights over the 64 local rows (wave 0)
    if (t < MB2) {
        float sc = spart[0][t] + spart[1][t] + spart[2][t] + spart[3][t];
        bool isB = (r0 + t) >= bsplit;
        float sA = isB ? -INFINITY : sc;
        float sB = isB ? sc : -INFINITY;
        float mA = sA, mB = sB;
#pragma unroll
        for (int off = 1; off < 64; off <<= 1) {
            mA = fmaxf(mA, __shfl_xor(mA, off, 64));
            mB = fmaxf(mB, __shfl_xor(mB, off, 64));
        }
        float wa = isB ? 0.f : __expf(sc - mA);
        float wb = isB ? __expf(sc - mB) : 0.f;
        float ssA = wa, ssB = wb;
#pragma unroll
        for (int off = 1; off < 64; off <<= 1) {
            ssA += __shfl_xor(ssA, off, 64);
            ssB += __shfl_xor(ssB, off, 64);
        }
        wLA[t] = wa;
        wLB[t] = wb;
        if (t == 0) {
            stats[(long)blk * 4 + 0] = mA;
            stats[(long)blk * 4 + 1] = ssA;
            stats[(long)blk * 4 + 2] = mB;
            stats[(long)blk * 4 + 3] = ssB;
        }
    }
    __syncthreads();
    // weighted reduce from register-held o: partial[col] = sum_rows w[row]*o[row][col]
    float psA[4] = {0.f, 0.f, 0.f, 0.f}, psB[4] = {0.f, 0.f, 0.f, 0.f};
#pragma unroll
    for (int mt = 0; mt < 4; ++mt)
#pragma unroll
        for (int rr = 0; rr < 4; ++rr) {
            int row = mt * 16 + quad * 4 + rr;
            float wa = wLA[row], wb = wLB[row];
#pragma unroll
            for (int nt = 0; nt < 4; ++nt) {
                float ov = unpk(obak[mt][nt][rr >> 1], rr & 1);
                psA[nt] += wa * ov;
                psB[nt] += wb * ov;
            }
        }
#pragma unroll
    for (int nt = 0; nt < 4; ++nt) {
        psA[nt] += __shfl_xor(psA[nt], 16, 64);
        psA[nt] += __shfl_xor(psA[nt], 32, 64);
        psB[nt] += __shfl_xor(psB[nt], 16, 64);
        psB[nt] += __shfl_xor(psB[nt], 32, 64);
    }
    if (quad == 0) {
#pragma unroll
        for (int nt = 0; nt < 4; ++nt)
            parts[((long)blk * 2 + 0) * D_SZ + wave * 64 + nt * 16 + l16] = psA[nt];
    } else if (quad == 1) {
#pragma unroll
        for (int nt = 0; nt < 4; ++nt)
            parts[((long)blk * 2 + 1) * D_SZ + wave * 64 + nt * 16 + l16] = psB[nt];
    }
}

// ---------------- KC: combine the 4 block-partials per batch (exact LSE merge) -------
__global__ void kc_combine(const float* __restrict__ parts, const float* __restrict__ stats,
                           float* __restrict__ out) {
    const int b = blockIdx.x, t = threadIdx.x;
    const int k0 = (b * L_SZ) / MB2;
    float m[4], s[4];
    int seg[4];
    float M = -INFINITY;
#pragma unroll
    for (int i = 0; i < 4; ++i) {
        int k = k0 + i;
        int bA = (k * MB2) / L_SZ;
        int sg = (bA == b) ? 0 : 1;
        seg[i] = sg;
        m[i] = stats[(long)k * 4 + sg * 2];
        s[i] = stats[(long)k * 4 + sg * 2 + 1];
        M = fmaxf(M, m[i]);
    }
    float denom = 0.f, accv = 0.f;
#pragma unroll
    for (int i = 0; i < 4; ++i) {
        float f = __expf(m[i] - M);
        denom += f * s[i];
        accv += f * parts[((long)(k0 + i) * 2 + seg[i]) * D_SZ + t];
    }
    out[(long)b * D_SZ + t] = accv / denom;
}

// ---------------- old K0 (MB=128) for mid-size-ws path ----------------
__launch_bounds__(256, 2)
__global__ void k0_h1pre(const int* __restrict__ nodes, const float* __restrict__ u2e,
                         const bf16* __restrict__ wf_a1h, const float* __restrict__ a1b,
                         float* __restrict__ h1p) {
    __shared__ __align__(16) bf16 abuf[MB * AST];
    __shared__ int idxl[MB];
    const int blk = blockIdx.x, t = threadIdx.x;
    const int wave = t >> 6, lane = t & 63, l16 = t & 15, quad = (t & 63) >> 4;
    if (t < MB) idxl[t] = nodes[blk * MB + t];
    __syncthreads();
    stage_rows(idxl, u2e, abuf, t);
    __syncthreads();
    f32x4 acc[8][4];
    zero_t<8>(acc);
    gemm_t<8, 8>(abuf, wf_a1h, 0, wave, lane, l16, quad, acc);
#pragma unroll
    for (int nt = 0; nt < 4; ++nt) {
        int col = (wave * 4 + nt) * 16 + l16;
        float ab = a1b[col];
#pragma unroll
        for (int mt = 0; mt < 8; ++mt)
#pragma unroll
            for (int r = 0; r < 4; ++r) {
                int row = mt * 16 + quad * 4 + r;
                h1p[(long)(blk * MB + row) * D_SZ + col] = acc[mt][nt][r] + ab;
            }
    }
}

// ---------------- old K1: gather + layer1 + layer2 -> o (mid-size ws) --------
__launch_bounds__(256, 2)
__global__ void k1_gemm12(const int* __restrict__ hua, const int* __restrict__ hr,
                          const float* __restrict__ attr, const float* __restrict__ r2e,
                          const bf16* __restrict__ wf_w1, const bf16* __restrict__ wf_w2,
                          const float* __restrict__ b1w, const float* __restrict__ b2w,
                          bf16* __restrict__ o_out) {
    __shared__ __align__(16) bf16 abuf[MB * AST];
    __shared__ int idx_ua[MB], idx_r[MB];
    const int blk = blockIdx.x, t = threadIdx.x;
    const int wave = t >> 6, lane = t & 63, l16 = t & 15, quad = (t & 63) >> 4;
    const long r0 = (long)blk * MB;
    if (t < MB) { idx_ua[t] = hua[r0 + t]; idx_r[t] = hr[r0 + t]; }
    __syncthreads();

    float bias1[4], bias2[4];
#pragma unroll
    for (int nt = 0; nt < 4; ++nt) {
        int col = (wave * 4 + nt) * 16 + l16;
        bias1[nt] = b1w[col];
        bias2[nt] = b2w[col];
    }

    f32x4 acc[8][4];
    zero_t<8>(acc);
    stage_rows(idx_ua, attr, abuf, t);
    __syncthreads();
    gemm_t<8, 16>(abuf, wf_w1, 0, wave, lane, l16, quad, acc);
    __syncthreads();
    stage_rows(idx_r, r2e, abuf, t);
    __syncthreads();
    gemm_t<8, 16>(abuf, wf_w1, 8, wave, lane, l16, quad, acc);
    __syncthreads();
    store_act_t<8>(abuf, acc, bias1, wave, l16, quad);
    __syncthreads();
    zero_t<8>(acc);
    gemm_t<8, 8>(abuf, wf_w2, 0, wave, lane, l16, quad, acc);
    __syncthreads();
    store_act_t<8>(abuf, acc, bias2, wave, l16, quad);
    __syncthreads();
#pragma unroll
    for (int it = 0; it < 16; ++it) {
        int g = it * 256 + t;
        int r = g >> 5, c = g & 31;
        *(bf16x8*)(o_out + (r0 + r) * D_SZ + c * 8) = *(const bf16x8*)(abuf + r * AST + c * 8);
    }
}

// ---------------- old K2: layer3 + layer4 + score (mid-size ws) --------------
__launch_bounds__(256, 2)
__global__ void k2_gemm34(const bf16* __restrict__ o_in,
                          const bf16* __restrict__ wf_a1l, const bf16* __restrict__ wf_a2f,
                          const float* __restrict__ h1p, const float* __restrict__ a2b,
                          const float* __restrict__ a3w, float* __restrict__ scores) {
    __shared__ __align__(16) bf16 abuf[MB * AST];
    __shared__ float hp[2][D_SZ];
    __shared__ float spart[4][MB];
    const int blk = blockIdx.x, t = threadIdx.x;
    const int wave = t >> 6, lane = t & 63, l16 = t & 15, quad = (t & 63) >> 4;
    const long r0 = (long)blk * MB;
    const int b0 = (int)(r0 / L_SZ);
    const int b1 = min(b0 + 1, 2047);
    const long bsplit = (long)(b0 + 1) * L_SZ;
    hp[0][t] = h1p[(long)b0 * D_SZ + t];
    hp[1][t] = h1p[(long)b1 * D_SZ + t];
#pragma unroll
    for (int it = 0; it < 16; ++it) {
        int g = it * 256 + t;
        int r = g >> 5, c = g & 31;
        *(bf16x8*)(abuf + r * AST + c * 8) = *(const bf16x8*)(o_in + (r0 + r) * D_SZ + c * 8);
    }
    __syncthreads();

    f32x4 acc[8][4];
    zero_t<8>(acc);
    gemm_t<8, 8>(abuf, wf_a1l, 0, wave, lane, l16, quad, acc);
    __syncthreads();
#pragma unroll
    for (int nt = 0; nt < 4; ++nt) {
        int col = (wave * 4 + nt) * 16 + l16;
#pragma unroll
        for (int mt = 0; mt < 8; ++mt)
#pragma unroll
            for (int r = 0; r < 4; ++r) {
                int row = mt * 16 + quad * 4 + r;
                float bias = ((r0 + row) >= bsplit) ? hp[1][col] : hp[0][col];
                float v = acc[mt][nt][r] + bias;
                v = v > 0.f ? v : 0.f;
                abuf[row * AST + col] = (bf16)v;
            }
    }
    __syncthreads();
    zero_t<8>(acc);
    gemm_t<8, 8>(abuf, wf_a2f, 0, wave, lane, l16, quad, acc);

    float bias4[4], a3[4];
#pragma unroll
    for (int nt = 0; nt < 4; ++nt) {
        int col = (wave * 4 + nt) * 16 + l16;
        bias4[nt] = a2b[col];
        a3[nt] = a3w[col];
    }
    float p[8][4];
#pragma unroll
    for (int mt = 0; mt < 8; ++mt)
#pragma unroll
        for (int r = 0; r < 4; ++r) {
            float s = 0.f;
#pragma unroll
            for (int nt = 0; nt < 4; ++nt) {
                float h = acc[mt][nt][r] + bias4[nt];
                h = h > 0.f ? h : 0.f;
                s += h * a3[nt];
            }
            p[mt][r] = s;
        }
#pragma unroll
    for (int off = 1; off < 16; off <<= 1)
#pragma unroll
        for (int mt = 0; mt < 8; ++mt)
#pragma unroll
            for (int r = 0; r < 4; ++r) p[mt][r] += __shfl_xor(p[mt][r], off, 16);
    if (l16 == 0) {
#pragma unroll
        for (int mt = 0; mt < 8; ++mt)
#pragma unroll
            for (int r = 0; r < 4; ++r)
                spart[wave][mt * 16 + quad * 4 + r] = p[mt][r];
    }
    __syncthreads();
    if (t < MB)
        scores[r0 + t] = spart[0][t] + spart[1][t] + spart[2][t] + spart[3][t];
}

// ---------------- K5: exact softmax + vectorized weighted reduce (mid-size ws) -------
__global__ void k5_reduce(const float* __restrict__ scores, const bf16* __restrict__ o_in,
                          float* __restrict__ out) {
    __shared__ float red[256];
    __shared__ float watt[256];
    __shared__ float racc[8][264];
    const int b = blockIdx.x, t = threadIdx.x;
    float s = (t < L_SZ) ? scores[(long)b * L_SZ + t] : -INFINITY;
    red[t] = s;
    __syncthreads();
    for (int off = 128; off > 0; off >>= 1) {
        if (t < off) red[t] = fmaxf(red[t], red[t + off]);
        __syncthreads();
    }
    float mx = red[0];
    __syncthreads();
    float w = (t < L_SZ) ? __expf(s - mx) : 0.f;
    watt[t] = w;
    red[t] = w;
    __syncthreads();
    for (int off = 128; off > 0; off >>= 1) {
        if (t < off) red[t] += red[t + off];
        __syncthreads();
    }
    float inv = 1.f / red[0];
    const int c8 = t & 31, rg = t >> 5;
    f32x4 a0 = {0.f, 0.f, 0.f, 0.f}, a1 = {0.f, 0.f, 0.f, 0.f};
    const bf16* ob = o_in + (long)b * L_SZ * D_SZ + c8 * 8;
#pragma unroll 5
    for (int l = rg; l < L_SZ; l += 8) {
        float wv = watt[l];
        bf16x8 v = *(const bf16x8*)(ob + (long)l * D_SZ);
        a0[0] += wv * (float)v[0]; a0[1] += wv * (float)v[1];
        a0[2] += wv * (float)v[2]; a0[3] += wv * (float)v[3];
        a1[0] += wv * (float)v[4]; a1[1] += wv * (float)v[5];
        a1[2] += wv * (float)v[6]; a1[3] += wv * (float)v[7];
    }
    *(f32x4*)(&racc[rg][c8 * 8]) = a0;
    *(f32x4*)(&racc[rg][c8 * 8 + 4]) = a1;
    __syncthreads();
    float r2 = 0.f;
#pragma unroll
    for (int g = 0; g < 8; ++g) r2 += racc[g][t];
    out[(long)b * D_SZ + t] = r2 * inv;
}

// ================= fallback fused kernel (R5 structure) for small ws =================
__device__ __forceinline__ void gather_half_f(const int* __restrict__ idxp,
                                              const float* __restrict__ table,
                                              bf16* __restrict__ buf, int l0, int t) {
#pragma unroll
    for (int it = 0; it < 6; ++it) {
        int g = it * 256 + t;
        int r = g >> 5, c = g & 31;
        int l = l0 + r;
        int li = l < L_SZ ? l : (L_SZ - 1);
        long row = idxp[li];
        const float* f = table + row * D_SZ + c * 8;
        f32x4 a = *(const f32x4*)f;
        f32x4 b2 = *(const f32x4*)(f + 4);
        bf16x8 v;
        v[0] = (bf16)a[0]; v[1] = (bf16)a[1]; v[2] = (bf16)a[2]; v[3] = (bf16)a[3];
        v[4] = (bf16)b2[0]; v[5] = (bf16)b2[1]; v[6] = (bf16)b2[2]; v[7] = (bf16)b2[3];
        *(bf16x8*)(buf + r * AST + c * 8) = v;
    }
}

__launch_bounds__(256, 3)
__global__ void ua_fused(const int* __restrict__ nodes, const int* __restrict__ hua,
                         const int* __restrict__ hr, const float* __restrict__ u2e,
                         const float* __restrict__ attr, const float* __restrict__ r2e,
                         const bf16* __restrict__ wf1, const bf16* __restrict__ wf2,
                         const bf16* __restrict__ wfa1, const bf16* __restrict__ wfa2,
                         const float* __restrict__ b1w, const float* __restrict__ b2w,
                         const float* __restrict__ att1w, const float* __restrict__ a1b,
                         const float* __restrict__ a2b, const float* __restrict__ att3w,
                         const float* __restrict__ a3bp, float* __restrict__ out) {
    __shared__ __align__(16) bf16 abuf[48 * AST];
    __shared__ __align__(16) bf16 obuf[48 * AST];
    __shared__ float h1pre[D_SZ];
    __shared__ float scratch[288];
    const int b = blockIdx.x, t = threadIdx.x;
    const int wave = t >> 6, lane = t & 63, l16 = t & 15, quad = (t & 63) >> 4;
    {
        int node = nodes[b];
        scratch[t] = u2e[(long)node * D_SZ + t];
        __syncthreads();
        float a = a1b[t];
        const float* wr = att1w + (long)t * 512 + 256;
#pragma unroll
        for (int k = 0; k < 256; k += 4) {
            f32x4 wv = *(const f32x4*)(wr + k);
            a += scratch[k] * wv[0] + scratch[k + 1] * wv[1] +
                 scratch[k + 2] * wv[2] + scratch[k + 3] * wv[3];
        }
        h1pre[t] = a;
        __syncthreads();
    }
    float bias1[4], bias2[4], bias3[4], bias4[4], a3[4];
#pragma unroll
    for (int nt = 0; nt < 4; ++nt) {
        int col = (wave * 4 + nt) * 16 + l16;
        bias1[nt] = b1w[col]; bias2[nt] = b2w[col]; bias3[nt] = h1pre[col];
        bias4[nt] = a2b[col]; a3[nt] = att3w[col];
    }
    const float a3bias = a3bp[0];
    const int* huab = hua + (long)b * L_SZ;
    const int* hrb = hr + (long)b * L_SZ;
    float accv = 0.f, srun = 0.f, mrun = -INFINITY;
    float* score_part = scratch;
    float* score_row = scratch + 192;
    float* wrow = scratch + 240;
    auto st3 = [&](bf16* buf, f32x4 (&acc)[3][4], const float* bias) {
#pragma unroll
        for (int mt = 0; mt < 3; ++mt)
#pragma unroll
            for (int nt = 0; nt < 4; ++nt) {
                int col = (wave * 4 + nt) * 16 + l16;
#pragma unroll
                for (int r = 0; r < 4; ++r) {
                    float v = acc[mt][nt][r] + bias[nt];
                    v = v > 0.f ? v : 0.f;
                    buf[(mt * 16 + quad * 4 + r) * AST + col] = (bf16)v;
                }
            }
    };
    for (int tile = 0; tile < 5; ++tile) {
        const int l0 = tile * 48;
        f32x4 acc[3][4];
        zero_t<3>(acc);
        gather_half_f(huab, attr, abuf, l0, t);
        __syncthreads();
        gemm_t<3, 16>(abuf, wf1, 0, wave, lane, l16, quad, acc);
        __syncthreads();
        gather_half_f(hrb, r2e, abuf, l0, t);
        __syncthreads();
        gemm_t<3, 16>(abuf, wf1, 8, wave, lane, l16, quad, acc);
        __syncthreads();
        st3(abuf, acc, bias1);
        __syncthreads();
        zero_t<3>(acc);
        gemm_t<3, 8>(abuf, wf2, 0, wave, lane, l16, quad, acc);
        st3(obuf, acc, bias2);
        __syncthreads();
        zero_t<3>(acc);
        gemm_t<3, 8>(obuf, wfa1, 0, wave, lane, l16, quad, acc);
        st3(abuf, acc, bias3);
        __syncthreads();
        zero_t<3>(acc);
        gemm_t<3, 8>(abuf, wfa2, 0, wave, lane, l16, quad, acc);
        float p[3][4];
#pragma unroll
        for (int mt = 0; mt < 3; ++mt)
#pragma unroll
            for (int r = 0; r < 4; ++r) {
                float s = 0.f;
#pragma unroll
                for (int nt = 0; nt < 4; ++nt) {
                    float h = acc[mt][nt][r] + bias4[nt];
                    h = h > 0.f ? h : 0.f;
                    s += h * a3[nt];
                }
                p[mt][r] = s;
            }
#pragma unroll
        for (int off = 1; off < 16; off <<= 1)
#pragma unroll
            for (int mt = 0; mt < 3; ++mt)
#pragma unroll
                for (int r = 0; r < 4; ++r) p[mt][r] += __shfl_xor(p[mt][r], off, 16);
        if (l16 == 0) {
#pragma unroll
            for (int mt = 0; mt < 3; ++mt)
#pragma unroll
                for (int r = 0; r < 4; ++r)
                    score_part[wave * 48 + mt * 16 + quad * 4 + r] = p[mt][r];
        }
        __syncthreads();
        if (t < 48) {
            float s = score_part[t] + score_part[48 + t] + score_part[96 + t] +
                      score_part[144 + t] + a3bias;
            score_row[t] = (l0 + t < L_SZ) ? s : -INFINITY;
        }
        __syncthreads();
        float tm = -INFINITY;
        for (int r = 0; r < 48; ++r) tm = fmaxf(tm, score_row[r]);
        float nm = fmaxf(mrun, tm);
        float factor = __expf(mrun - nm);
        if (t < 48) wrow[t] = __expf(score_row[t] - nm);
        __syncthreads();
        float wsum = 0.f, av = 0.f;
#pragma unroll 8
        for (int r = 0; r < 48; ++r) {
            float w = wrow[r];
            wsum += w;
            av += w * (float)obuf[r * AST + t];
        }
        accv = accv * factor + av;
        srun = srun * factor + wsum;
        mrun = nm;
        __syncthreads();
    }
    out[(long)b * D_SZ + t] = accv / srun;
}

extern "C" void kernel_launch(void* const* d_in, const int* in_sizes, int n_in,
                              void* d_out, int out_size, void* d_ws, size_t ws_size,
                              hipStream_t stream) {
    const int* nodes = (const int*)d_in[0];
    const int* hua = (const int*)d_in[1];
    const int* hr = (const int*)d_in[2];
    // d_in[3] history_uat unused
    const float* u2e = (const float*)d_in[4];
    const float* attr = (const float*)d_in[5];
    const float* r2e = (const float*)d_in[6];
    const float* w1 = (const float*)d_in[7];
    const float* b1 = (const float*)d_in[8];
    const float* w2 = (const float*)d_in[9];
    const float* b2 = (const float*)d_in[10];
    const float* a1w = (const float*)d_in[11];
    const float* a1b = (const float*)d_in[12];
    const float* a2w = (const float*)d_in[13];
    const float* a2b = (const float*)d_in[14];
    const float* a3w = (const float*)d_in[15];
    const float* a3b = (const float*)d_in[16];
    char* ws = (char*)d_ws;
    bf16* wf_w2 = (bf16*)(ws + WS_W2F);
    bf16* wf_a1l = (bf16*)(ws + WS_A1L);
    bf16* wf_a1h = (bf16*)(ws + WS_A1H);
    bf16* wf_a2f = (bf16*)(ws + WS_A2F);
    bf16* wf_w1a = (bf16*)(ws + WS_W1A);
    bf16* wf_w1 = (bf16*)(ws + WS_W1F);

    if (ws_size >= (size_t)WS_NEED_NEW) {
        float* Rg = (float*)(ws + WS_R);
        float* h1p = (float*)(ws + WS_H1P);
        float* parts = (float*)(ws + WS_PART);
        float* stats = (float*)(ws + WS_STAT);
        bf16* Pt = (bf16*)(ws + WS_P);
        swizzle_all<<<161, 256, 0, stream>>>(w2, a1w, a2w, w1,
                                             wf_w2, wf_a1l, wf_a2f, wf_a1h, wf_w1a,
                                             r2e, b1, Rg);
        kpre_k0<<<NPB64 + NK0, 256, 0, stream>>>(attr, wf_w1a, Pt,
                                                 nodes, u2e, wf_a1h, a1b, h1p);
        k1f_fused<<<NROWS / MB2, 256, 0, stream>>>(hua, hr, Pt, Rg, wf_w2, wf_a1l,
                                                   wf_a2f, h1p, b2, a2b, a3w,
                                                   parts, stats);
        kc_combine<<<2048, 256, 0, stream>>>(parts, stats, (float*)d_out);
    } else if (ws_size >= (size_t)WS_NEED_OLD) {
        float* h1p = (float*)(ws + WS_H1P);
        float* scores = (float*)(ws + WS_SCR);
        bf16* obuf = (bf16*)(ws + WS_O);
        swizzle_kernel<<<32, 256, 0, stream>>>(w2, wf_w2, 8, 256, 0, 8192);
        swizzle_kernel<<<32, 256, 0, stream>>>(a1w, wf_a1l, 8, 512, 0, 8192);
        swizzle_kernel<<<32, 256, 0, stream>>>(a2w, wf_a2f, 8, 256, 0, 8192);
        swizzle_kernel<<<64, 256, 0, stream>>>(w1, wf_w1, 16, 512, 0, 16384);
        swizzle_kernel<<<32, 256, 0, stream>>>(a1w, wf_a1h, 8, 512, 256, 8192);
        k0_h1pre<<<2048 / MB, 256, 0, stream>>>(nodes, u2e, wf_a1h, a1b, h1p);
        k1_gemm12<<<NROWS / MB, 256, 0, stream>>>(hua, hr, attr, r2e, wf_w1, wf_w2,
                                                  b1, b2, obuf);
        k2_gemm34<<<NROWS / MB, 256, 0, stream>>>(obuf, wf_a1l, wf_a2f, h1p, a2b,
                                                  a3w, scores);
        k5_reduce<<<2048, 256, 0, stream>>>(scores, obuf, (float*)d_out);
    } else {
        swizzle_kernel<<<32, 256, 0, stream>>>(w2, wf_w2, 8, 256, 0, 8192);
        swizzle_kernel<<<32, 256, 0, stream>>>(a1w, wf_a1l, 8, 512, 0, 8192);
        swizzle_kernel<<<32, 256, 0, stream>>>(a2w, wf_a2f, 8, 256, 0, 8192);
        swizzle_kernel<<<64, 256, 0, stream>>>(w1, wf_w1, 16, 512, 0, 16384);
        ua_fused<<<2048, 256, 0, stream>>>(nodes, hua, hr, u2e, attr, r2e,
                                           wf_w1, wf_w2, wf_a1l, wf_a2f,
                                           b1, b2, a1w, a1b, a2b, a3w, a3b,
                                           (float*)d_out);
    }
}

// Round 5
// 525.028 us; speedup vs baseline: 1.1414x; 1.1414x over previous
//
#include <hip/hip_runtime.h>
#include <hip/hip_bf16.h>

typedef __bf16 bf16;
typedef __bf16 bf16x8 __attribute__((ext_vector_type(8)));
typedef float f32x4 __attribute__((ext_vector_type(4)));

#define L_SZ 200
#define D_SZ 256
#define NROWS (2048 * 200)
#define MB 128           // rows per block in old-path kernels
#define MB2 64           // rows per block in k1f / kpre_k0
#define AST 264          // LDS activation row stride (bf16 elems)
#define N_ATTR 50000
#define NPB ((N_ATTR + MB - 1) / MB)      // old-path P blocks
#define NPB64 ((N_ATTR + MB2 - 1) / MB2)  // 782 P blocks (new path)
#define NK0 (2048 / MB2)                  // 32 h1pre blocks

// ---- ws layout (byte offsets) ----
#define WS_W2F 0u             // w2   swizzled 256x256 -> 131072
#define WS_A1L 131072u        // att1[:, :256] -> 131072
#define WS_A1H 262144u        // att1[:, 256:] -> 131072
#define WS_A2F 393216u        // att2 256x256 -> 131072
#define WS_W1A 524288u        // w1[:, :256] swizzled (KT=8) -> 131072
#define WS_W1F 655360u        // w1 full swizzled (KT=16) -> 262144 (old/fallback)
#define WS_R   917504u        // R[5][256] fp32 -> 5120 (pad 8192)
#define WS_H1P 925696u        // h1pre fp32 [2048][256] -> 2097152
#define WS_SCR 3022848u       // scores fp32 [409600] -> 1638400
#define WS_O   4661248u       // o bf16 [409600][256] -> 209715200
#define WS_P   214376448u     // P bf16 [50000][256] -> 25600000
#define WS_NEED_OLD 214376448u
#define WS_NEED_NEW 239976448u

// ---------------- weight pre-swizzle (fp32 -> bf16 MFMA B-fragments) ----------------
__device__ __forceinline__ void swz_one(const float* __restrict__ W, bf16* __restrict__ dst,
                                        int KT, int ldw, int koff, int g) {
    int lane = g & 63;
    int kt = (g >> 6) % KT;
    int nt = g / (64 * KT);
    int n = nt * 16 + (lane & 15);
    int k = kt * 32 + (lane >> 4) * 8;
    const float* src = W + (long)n * ldw + koff + k;
    f32x4 a = *(const f32x4*)src;
    f32x4 b = *(const f32x4*)(src + 4);
    bf16x8 v;
    v[0] = (bf16)a[0]; v[1] = (bf16)a[1]; v[2] = (bf16)a[2]; v[3] = (bf16)a[3];
    v[4] = (bf16)b[0]; v[5] = (bf16)b[1]; v[6] = (bf16)b[2]; v[7] = (bf16)b[3];
    *(bf16x8*)(dst + (long)g * 8) = v;
}

__global__ void swizzle_kernel(const float* __restrict__ W, bf16* __restrict__ dst,
                               int KT, int ldw, int koff, int total) {
    int g = blockIdx.x * blockDim.x + threadIdx.x;
    if (g >= total) return;
    swz_one(W, dst, KT, ldw, koff, g);
}

// all 5 new-path swizzles (KT=8, 8192 frags each) + R precompute in one launch.
__global__ void swizzle_all(const float* __restrict__ w2, const float* __restrict__ a1w,
                            const float* __restrict__ a2w, const float* __restrict__ w1,
                            bf16* __restrict__ wf_w2, bf16* __restrict__ wf_a1l,
                            bf16* __restrict__ wf_a2f, bf16* __restrict__ wf_a1h,
                            bf16* __restrict__ wf_w1a,
                            const float* __restrict__ r2e, const float* __restrict__ b1w,
                            float* __restrict__ Rg) {
    __shared__ float e[5 * D_SZ];
    const int blk = blockIdx.x, t = threadIdx.x;
    if (blk == 160) {
        // R[r][n] = b1[n] + w1[n][256:] . r2e[r]  (fp32 exact)
        for (int i = t; i < 5 * D_SZ; i += 256) e[i] = r2e[i];
        __syncthreads();
        const float* wr = w1 + (long)t * 512 + 256;
        float bb = b1w[t];
        for (int r = 0; r < 5; ++r) {
            float a = bb;
            const float* er = e + r * D_SZ;
#pragma unroll
            for (int k = 0; k < D_SZ; k += 4) {
                f32x4 wv = *(const f32x4*)(wr + k);
                a += er[k] * wv[0] + er[k + 1] * wv[1] + er[k + 2] * wv[2] + er[k + 3] * wv[3];
            }
            Rg[r * D_SZ + t] = a;
        }
        return;
    }
    int job = blk >> 5, lb = blk & 31;
    int g = lb * 256 + t;
    const float* W; bf16* dst; int ldw, koff;
    switch (job) {
        case 0:  W = w2;  dst = wf_w2;  ldw = 256; koff = 0;   break;
        case 1:  W = a1w; dst = wf_a1l; ldw = 512; koff = 0;   break;
        case 2:  W = a2w; dst = wf_a2f; ldw = 256; koff = 0;   break;
        case 3:  W = a1w; dst = wf_a1h; ldw = 512; koff = 256; break;
        default: W = w1;  dst = wf_w1a; ldw = 512; koff = 0;   break;
    }
    swz_one(W, dst, 8, ldw, koff, g);
}

// ---------------- shared device helpers ----------------
__device__ __forceinline__ void stage_rows(const int* __restrict__ idxl,
                                           const float* __restrict__ table,
                                           bf16* __restrict__ buf, int t) {
#pragma unroll
    for (int it = 0; it < 16; ++it) {
        int g = it * 256 + t;
        int r = g >> 5;          // 0..127
        int c = g & 31;          // 8-float chunk
        long row = idxl[r];
        const float* f = table + row * D_SZ + c * 8;
        f32x4 a = *(const f32x4*)f;
        f32x4 b = *(const f32x4*)(f + 4);
        bf16x8 v;
        v[0] = (bf16)a[0]; v[1] = (bf16)a[1]; v[2] = (bf16)a[2]; v[3] = (bf16)a[3];
        v[4] = (bf16)b[0]; v[5] = (bf16)b[1]; v[6] = (bf16)b[2]; v[7] = (bf16)b[3];
        *(bf16x8*)(buf + r * AST + c * 8) = v;
    }
}

template <int MT, int KTOT>
__device__ __forceinline__ void gemm_t(const bf16* __restrict__ abase,
                                       const bf16* __restrict__ wfrag, int koff_t,
                                       int wave, int lane, int l16, int quad,
                                       f32x4 (&acc)[MT][4]) {
    const bf16* wbase = wfrag + ((long)(wave * 4) * KTOT + koff_t) * 512 + lane * 8;
    bf16x8 bc[4], bn[4];
#pragma unroll
    for (int nt = 0; nt < 4; ++nt)
        bc[nt] = *(const bf16x8*)(wbase + (long)nt * KTOT * 512);
#pragma unroll
    for (int kt = 0; kt < 8; ++kt) {
        if (kt < 7) {
#pragma unroll
            for (int nt = 0; nt < 4; ++nt)
                bn[nt] = *(const bf16x8*)(wbase + ((long)nt * KTOT + kt + 1) * 512);
        }
        bf16x8 a[MT];
#pragma unroll
        for (int mt = 0; mt < MT; ++mt)
            a[mt] = *(const bf16x8*)(abase + (mt * 16 + l16) * AST + kt * 32 + quad * 8);
#pragma unroll
        for (int nt = 0; nt < 4; ++nt)
#pragma unroll
            for (int mt = 0; mt < MT; ++mt)
                acc[mt][nt] = __builtin_amdgcn_mfma_f32_16x16x32_bf16(a[mt], bc[nt], acc[mt][nt], 0, 0, 0);
#pragma unroll
        for (int nt = 0; nt < 4; ++nt) bc[nt] = bn[nt];
    }
}

template <int MT>
__device__ __forceinline__ void zero_t(f32x4 (&acc)[MT][4]) {
    f32x4 z = {0.f, 0.f, 0.f, 0.f};
#pragma unroll
    for (int mt = 0; mt < MT; ++mt)
#pragma unroll
        for (int nt = 0; nt < 4; ++nt) acc[mt][nt] = z;
}

template <int MT>
__device__ __forceinline__ void store_act_t(bf16* __restrict__ buf, f32x4 (&acc)[MT][4],
                                            const float* bias, int wave, int l16, int quad) {
#pragma unroll
    for (int mt = 0; mt < MT; ++mt)
#pragma unroll
        for (int nt = 0; nt < 4; ++nt) {
            int col = (wave * 4 + nt) * 16 + l16;
#pragma unroll
            for (int r = 0; r < 4; ++r) {
                int row = mt * 16 + quad * 4 + r;
                float v = acc[mt][nt][r] + bias[nt];
                v = v > 0.f ? v : 0.f;
                buf[row * AST + col] = (bf16)v;
            }
        }
}

template <int MT>
__device__ __forceinline__ void store_lin_t(bf16* __restrict__ buf, f32x4 (&acc)[MT][4],
                                            int wave, int l16, int quad) {
#pragma unroll
    for (int mt = 0; mt < MT; ++mt)
#pragma unroll
        for (int nt = 0; nt < 4; ++nt) {
            int col = (wave * 4 + nt) * 16 + l16;
#pragma unroll
            for (int r = 0; r < 4; ++r) {
                int row = mt * 16 + quad * 4 + r;
                buf[row * AST + col] = (bf16)acc[mt][nt][r];
            }
        }
}

// ---------------- Kpre+K0 (new path, 64-row tiles, 4 blocks/CU) ----------------
// blocks [0, NPB64): P[a] = attr[a] . W1a^T ; blocks [NPB64, NPB64+NK0): h1pre
__launch_bounds__(256, 4)
__global__ void kpre_k0(const float* __restrict__ attr, const bf16* __restrict__ wf_w1a,
                        bf16* __restrict__ Pt,
                        const int* __restrict__ nodes, const float* __restrict__ u2e,
                        const bf16* __restrict__ wf_a1h, const float* __restrict__ a1b,
                        float* __restrict__ h1p) {
    __shared__ __align__(16) bf16 abuf[MB2 * AST];
    const int blk = blockIdx.x, t = threadIdx.x;
    const int wave = t >> 6, lane = t & 63, l16 = t & 15, quad = (t & 63) >> 4;
    const bool isP = blk < NPB64;
    const int blk0 = blk - NPB64;
    const float* table = isP ? attr : u2e;
    // stage 64 fp32 rows -> bf16 LDS
#pragma unroll
    for (int it = 0; it < 8; ++it) {
        int g = it * 256 + t;
        int r = g >> 5, c = g & 31;
        long row;
        if (isP) { row = (long)blk * MB2 + r; if (row >= N_ATTR) row = N_ATTR - 1; }
        else row = nodes[blk0 * MB2 + r];
        const float* f = table + row * D_SZ + c * 8;
        f32x4 a = *(const f32x4*)f;
        f32x4 b = *(const f32x4*)(f + 4);
        bf16x8 v;
        v[0] = (bf16)a[0]; v[1] = (bf16)a[1]; v[2] = (bf16)a[2]; v[3] = (bf16)a[3];
        v[4] = (bf16)b[0]; v[5] = (bf16)b[1]; v[6] = (bf16)b[2]; v[7] = (bf16)b[3];
        *(bf16x8*)(abuf + r * AST + c * 8) = v;
    }
    __syncthreads();
    f32x4 acc[4][4];
    zero_t<4>(acc);
    gemm_t<4, 8>(abuf, isP ? wf_w1a : wf_a1h, 0, wave, lane, l16, quad, acc);
    if (isP) {
        __syncthreads();
        store_lin_t<4>(abuf, acc, wave, l16, quad);
        __syncthreads();
#pragma unroll
        for (int it = 0; it < 8; ++it) {
            int g = it * 256 + t;
            int r = g >> 5, c = g & 31;
            long row = (long)blk * MB2 + r;
            if (row < N_ATTR)
                *(bf16x8*)(Pt + row * D_SZ + c * 8) = *(const bf16x8*)(abuf + r * AST + c * 8);
        }
    } else {
#pragma unroll
        for (int nt = 0; nt < 4; ++nt) {
            int col = (wave * 4 + nt) * 16 + l16;
            float ab = a1b[col];
#pragma unroll
            for (int mt = 0; mt < 4; ++mt)
#pragma unroll
                for (int r = 0; r < 4; ++r) {
                    int row = mt * 16 + quad * 4 + r;
                    h1p[(long)(blk0 * MB2 + row) * D_SZ + col] = acc[mt][nt][r] + ab;
                }
        }
    }
}

// ---------------- K1F: gather P/R -> x -> o -> h1 -> h2 -> score (R2 structure) ------
// o is written to global with NON-TEMPORAL stores: the 210 MB o stream must not
// write-allocate in L2/L3, or it evicts the 25.6 MB P table (R2: FETCH 186 MB vs
// ~30 MB ideal -> P was thrashed out of L3 by the o write stream).
__launch_bounds__(256, 4)
__global__ void k1f_fused(const int* __restrict__ hua, const int* __restrict__ hr,
                          const bf16* __restrict__ Pt, const float* __restrict__ Rg,
                          const bf16* __restrict__ wf_w2, const bf16* __restrict__ wf_a1l,
                          const bf16* __restrict__ wf_a2f, const float* __restrict__ h1p,
                          const float* __restrict__ b2w, const float* __restrict__ a2b,
                          const float* __restrict__ a3w,
                          bf16* __restrict__ o_out, float* __restrict__ scores) {
    __shared__ __align__(16) bf16 abuf[MB2 * AST];     // 33792 B
    __shared__ int idx_ua[MB2], idx_r[MB2];            // 512 B
    __shared__ float spart[4][MB2];                    // 1024 B -> 35328 B, 4 blk/CU
    const int blk = blockIdx.x, t = threadIdx.x;
    const int wave = t >> 6, lane = t & 63, l16 = t & 15, quad = (t & 63) >> 4;
    const long r0 = (long)blk * MB2;
    const int b0 = (int)(r0 / L_SZ);
    const int b1i = min(b0 + 1, 2047);
    const long bsplit = (long)(b0 + 1) * L_SZ;
    if (t < MB2) { idx_ua[t] = hua[r0 + t]; idx_r[t] = hr[r0 + t]; }
    __syncthreads();
    // stage x = relu(P[hua] + R[hr]) into abuf  (layer1 is a gather + add; R via L1)
#pragma unroll
    for (int it = 0; it < 4; ++it) {
        int g = it * 256 + t;
        int r = g >> 4, c = g & 15;          // 16 lanes per row, 32B chunks
        long row = idx_ua[r];
        const bf16* pp = Pt + row * D_SZ + c * 16;
        bf16x8 v0 = *(const bf16x8*)pp;
        bf16x8 v1 = *(const bf16x8*)(pp + 8);
        const float* Rr = Rg + idx_r[r] * D_SZ + c * 16;
        f32x4 ra = *(const f32x4*)(Rr);
        f32x4 rb = *(const f32x4*)(Rr + 4);
        f32x4 rc = *(const f32x4*)(Rr + 8);
        f32x4 rd = *(const f32x4*)(Rr + 12);
        bf16x8 o0, o1;
#pragma unroll
        for (int j = 0; j < 4; ++j) {
            float a = (float)v0[j] + ra[j];
            float b = (float)v0[j + 4] + rb[j];
            float cc = (float)v1[j] + rc[j];
            float d = (float)v1[j + 4] + rd[j];
            o0[j]     = (bf16)(a > 0.f ? a : 0.f);
            o0[j + 4] = (bf16)(b > 0.f ? b : 0.f);
            o1[j]     = (bf16)(cc > 0.f ? cc : 0.f);
            o1[j + 4] = (bf16)(d > 0.f ? d : 0.f);
        }
        *(bf16x8*)(abuf + r * AST + c * 16) = o0;
        *(bf16x8*)(abuf + r * AST + c * 16 + 8) = o1;
    }
    __syncthreads();

    f32x4 acc[4][4];
    zero_t<4>(acc);
    gemm_t<4, 8>(abuf, wf_w2, 0, wave, lane, l16, quad, acc);   // layer2
    __syncthreads();                                            // all reads of x done
    float bias2[4];
#pragma unroll
    for (int nt = 0; nt < 4; ++nt) bias2[nt] = b2w[(wave * 4 + nt) * 16 + l16];
    store_act_t<4>(abuf, acc, bias2, wave, l16, quad);          // o -> abuf
    __syncthreads();
    // o tile -> global, NON-TEMPORAL (no L2/L3 allocation); abuf (o) stays for layer3
#pragma unroll
    for (int it = 0; it < 8; ++it) {
        int g = it * 256 + t;
        int r = g >> 5, c = g & 31;
        bf16x8 v = *(const bf16x8*)(abuf + r * AST + c * 8);
        __builtin_nontemporal_store(v, (bf16x8*)(o_out + (r0 + r) * D_SZ + c * 8));
    }
    zero_t<4>(acc);
    gemm_t<4, 8>(abuf, wf_a1l, 0, wave, lane, l16, quad, acc);  // layer3 (low half)
    __syncthreads();                                            // all reads of o done
    // h1 = relu(acc + h1pre[b(row)][col]) -> abuf  (h1p direct, L2-hit)
    float h0v[4], h1v[4];
#pragma unroll
    for (int nt = 0; nt < 4; ++nt) {
        int col = (wave * 4 + nt) * 16 + l16;
        h0v[nt] = h1p[(long)b0 * D_SZ + col];
        h1v[nt] = h1p[(long)b1i * D_SZ + col];
    }
#pragma unroll
    for (int nt = 0; nt < 4; ++nt) {
        int col = (wave * 4 + nt) * 16 + l16;
#pragma unroll
        for (int mt = 0; mt < 4; ++mt)
#pragma unroll
            for (int r = 0; r < 4; ++r) {
                int row = mt * 16 + quad * 4 + r;
                float bias = ((r0 + row) >= bsplit) ? h1v[nt] : h0v[nt];
                float v = acc[mt][nt][r] + bias;
                v = v > 0.f ? v : 0.f;
                abuf[row * AST + col] = (bf16)v;
            }
    }
    __syncthreads();
    zero_t<4>(acc);
    gemm_t<4, 8>(abuf, wf_a2f, 0, wave, lane, l16, quad, acc);  // layer4

    float bias4[4], a3[4];
#pragma unroll
    for (int nt = 0; nt < 4; ++nt) {
        int col = (wave * 4 + nt) * 16 + l16;
        bias4[nt] = a2b[col];
        a3[nt] = a3w[col];
    }
    float p[4][4];
#pragma unroll
    for (int mt = 0; mt < 4; ++mt)
#pragma unroll
        for (int r = 0; r < 4; ++r) {
            float s = 0.f;
#pragma unroll
            for (int nt = 0; nt < 4; ++nt) {
                float h = acc[mt][nt][r] + bias4[nt];
                h = h > 0.f ? h : 0.f;
                s += h * a3[nt];
            }
            p[mt][r] = s;
        }
#pragma unroll
    for (int off = 1; off < 16; off <<= 1)
#pragma unroll
        for (int mt = 0; mt < 4; ++mt)
#pragma unroll
            for (int r = 0; r < 4; ++r) p[mt][r] += __shfl_xor(p[mt][r], off, 16);
    if (l16 == 0) {
#pragma unroll
        for (int mt = 0; mt < 4; ++mt)
#pragma unroll
            for (int r = 0; r < 4; ++r)
                spart[wave][mt * 16 + quad * 4 + r] = p[mt][r];
    }
    __syncthreads();
    if (t < MB2)   // att3_b omitted: constant shift is softmax-invariant
        scores[r0 + t] = spart[0][t] + spart[1][t] + spart[2][t] + spart[3][t];
}

// ---------------- old K0 (MB=128) for mid-size-ws path ----------------
__launch_bounds__(256, 2)
__global__ void k0_h1pre(const int* __restrict__ nodes, const float* __restrict__ u2e,
                         const bf16* __restrict__ wf_a1h, const float* __restrict__ a1b,
                         float* __restrict__ h1p) {
    __shared__ __align__(16) bf16 abuf[MB * AST];
    __shared__ int idxl[MB];
    const int blk = blockIdx.x, t = threadIdx.x;
    const int wave = t >> 6, lane = t & 63, l16 = t & 15, quad = (t & 63) >> 4;
    if (t < MB) idxl[t] = nodes[blk * MB + t];
    __syncthreads();
    stage_rows(idxl, u2e, abuf, t);
    __syncthreads();
    f32x4 acc[8][4];
    zero_t<8>(acc);
    gemm_t<8, 8>(abuf, wf_a1h, 0, wave, lane, l16, quad, acc);
#pragma unroll
    for (int nt = 0; nt < 4; ++nt) {
        int col = (wave * 4 + nt) * 16 + l16;
        float ab = a1b[col];
#pragma unroll
        for (int mt = 0; mt < 8; ++mt)
#pragma unroll
            for (int r = 0; r < 4; ++r) {
                int row = mt * 16 + quad * 4 + r;
                h1p[(long)(blk * MB + row) * D_SZ + col] = acc[mt][nt][r] + ab;
            }
    }
}

// ---------------- old K1: gather + layer1 + layer2 -> o (mid-size ws) --------
__launch_bounds__(256, 2)
__global__ void k1_gemm12(const int* __restrict__ hua, const int* __restrict__ hr,
                          const float* __restrict__ attr, const float* __restrict__ r2e,
                          const bf16* __restrict__ wf_w1, const bf16* __restrict__ wf_w2,
                          const float* __restrict__ b1w, const float* __restrict__ b2w,
                          bf16* __restrict__ o_out) {
    __shared__ __align__(16) bf16 abuf[MB * AST];
    __shared__ int idx_ua[MB], idx_r[MB];
    const int blk = blockIdx.x, t = threadIdx.x;
    const int wave = t >> 6, lane = t & 63, l16 = t & 15, quad = (t & 63) >> 4;
    const long r0 = (long)blk * MB;
    if (t < MB) { idx_ua[t] = hua[r0 + t]; idx_r[t] = hr[r0 + t]; }
    __syncthreads();

    float bias1[4], bias2[4];
#pragma unroll
    for (int nt = 0; nt < 4; ++nt) {
        int col = (wave * 4 + nt) * 16 + l16;
        bias1[nt] = b1w[col];
        bias2[nt] = b2w[col];
    }

    f32x4 acc[8][4];
    zero_t<8>(acc);
    stage_rows(idx_ua, attr, abuf, t);
    __syncthreads();
    gemm_t<8, 16>(abuf, wf_w1, 0, wave, lane, l16, quad, acc);
    __syncthreads();
    stage_rows(idx_r, r2e, abuf, t);
    __syncthreads();
    gemm_t<8, 16>(abuf, wf_w1, 8, wave, lane, l16, quad, acc);
    __syncthreads();
    store_act_t<8>(abuf, acc, bias1, wave, l16, quad);
    __syncthreads();
    zero_t<8>(acc);
    gemm_t<8, 8>(abuf, wf_w2, 0, wave, lane, l16, quad, acc);
    __syncthreads();
    store_act_t<8>(abuf, acc, bias2, wave, l16, quad);
    __syncthreads();
#pragma unroll
    for (int it = 0; it < 16; ++it) {
        int g = it * 256 + t;
        int r = g >> 5, c = g & 31;
        *(bf16x8*)(o_out + (r0 + r) * D_SZ + c * 8) = *(const bf16x8*)(abuf + r * AST + c * 8);
    }
}

// ---------------- old K2: layer3 + layer4 + score (mid-size ws) --------------
__launch_bounds__(256, 2)
__global__ void k2_gemm34(const bf16* __restrict__ o_in,
                          const bf16* __restrict__ wf_a1l, const bf16* __restrict__ wf_a2f,
                          const float* __restrict__ h1p, const float* __restrict__ a2b,
                          const float* __restrict__ a3w, float* __restrict__ scores) {
    __shared__ __align__(16) bf16 abuf[MB * AST];
    __shared__ float hp[2][D_SZ];
    __shared__ float spart[4][MB];
    const int blk = blockIdx.x, t = threadIdx.x;
    const int wave = t >> 6, lane = t & 63, l16 = t & 15, quad = (t & 63) >> 4;
    const long r0 = (long)blk * MB;
    const int b0 = (int)(r0 / L_SZ);
    const int b1 = min(b0 + 1, 2047);
    const long bsplit = (long)(b0 + 1) * L_SZ;
    hp[0][t] = h1p[(long)b0 * D_SZ + t];
    hp[1][t] = h1p[(long)b1 * D_SZ + t];
#pragma unroll
    for (int it = 0; it < 16; ++it) {
        int g = it * 256 + t;
        int r = g >> 5, c = g & 31;
        *(bf16x8*)(abuf + r * AST + c * 8) = *(const bf16x8*)(o_in + (r0 + r) * D_SZ + c * 8);
    }
    __syncthreads();

    f32x4 acc[8][4];
    zero_t<8>(acc);
    gemm_t<8, 8>(abuf, wf_a1l, 0, wave, lane, l16, quad, acc);
    __syncthreads();
#pragma unroll
    for (int nt = 0; nt < 4; ++nt) {
        int col = (wave * 4 + nt) * 16 + l16;
#pragma unroll
        for (int mt = 0; mt < 8; ++mt)
#pragma unroll
            for (int r = 0; r < 4; ++r) {
                int row = mt * 16 + quad * 4 + r;
                float bias = ((r0 + row) >= bsplit) ? hp[1][col] : hp[0][col];
                float v = acc[mt][nt][r] + bias;
                v = v > 0.f ? v : 0.f;
                abuf[row * AST + col] = (bf16)v;
            }
    }
    __syncthreads();
    zero_t<8>(acc);
    gemm_t<8, 8>(abuf, wf_a2f, 0, wave, lane, l16, quad, acc);

    float bias4[4], a3[4];
#pragma unroll
    for (int nt = 0; nt < 4; ++nt) {
        int col = (wave * 4 + nt) * 16 + l16;
        bias4[nt] = a2b[col];
        a3[nt] = a3w[col];
    }
    float p[8][4];
#pragma unroll
    for (int mt = 0; mt < 8; ++mt)
#pragma unroll
        for (int r = 0; r < 4; ++r) {
            float s = 0.f;
#pragma unroll
            for (int nt = 0; nt < 4; ++nt) {
                float h = acc[mt][nt][r] + bias4[nt];
                h = h > 0.f ? h : 0.f;
                s += h * a3[nt];
            }
            p[mt][r] = s;
        }
#pragma unroll
    for (int off = 1; off < 16; off <<= 1)
#pragma unroll
        for (int mt = 0; mt < 8; ++mt)
#pragma unroll
            for (int r = 0; r < 4; ++r) p[mt][r] += __shfl_xor(p[mt][r], off, 16);
    if (l16 == 0) {
#pragma unroll
        for (int mt = 0; mt < 8; ++mt)
#pragma unroll
            for (int r = 0; r < 4; ++r)
                spart[wave][mt * 16 + quad * 4 + r] = p[mt][r];
    }
    __syncthreads();
    if (t < MB)
        scores[r0 + t] = spart[0][t] + spart[1][t] + spart[2][t] + spart[3][t];
}

// ---------------- K5: exact softmax over L + vectorized weighted reduce --------------
__global__ void k5_reduce(const float* __restrict__ scores, const bf16* __restrict__ o_in,
                          float* __restrict__ out) {
    __shared__ float red[256];
    __shared__ float watt[256];
    __shared__ float racc[8][264];
    const int b = blockIdx.x, t = threadIdx.x;
    float s = (t < L_SZ) ? scores[(long)b * L_SZ + t] : -INFINITY;
    red[t] = s;
    __syncthreads();
    for (int off = 128; off > 0; off >>= 1) {
        if (t < off) red[t] = fmaxf(red[t], red[t + off]);
        __syncthreads();
    }
    float mx = red[0];
    __syncthreads();
    float w = (t < L_SZ) ? __expf(s - mx) : 0.f;
    watt[t] = w;
    red[t] = w;
    __syncthreads();
    for (int off = 128; off > 0; off >>= 1) {
        if (t < off) red[t] += red[t + off];
        __syncthreads();
    }
    float inv = 1.f / red[0];
    // vectorized weighted sum: thread = (row-group rg, 8-col chunk c8); 25 bf16x8 loads
    const int c8 = t & 31, rg = t >> 5;
    f32x4 a0 = {0.f, 0.f, 0.f, 0.f}, a1 = {0.f, 0.f, 0.f, 0.f};
    const bf16* ob = o_in + (long)b * L_SZ * D_SZ + c8 * 8;
#pragma unroll 5
    for (int l = rg; l < L_SZ; l += 8) {
        float wv = watt[l];
        bf16x8 v = *(const bf16x8*)(ob + (long)l * D_SZ);
        a0[0] += wv * (float)v[0]; a0[1] += wv * (float)v[1];
        a0[2] += wv * (float)v[2]; a0[3] += wv * (float)v[3];
        a1[0] += wv * (float)v[4]; a1[1] += wv * (float)v[5];
        a1[2] += wv * (float)v[6]; a1[3] += wv * (float)v[7];
    }
    *(f32x4*)(&racc[rg][c8 * 8]) = a0;
    *(f32x4*)(&racc[rg][c8 * 8 + 4]) = a1;
    __syncthreads();
    float r2 = 0.f;
#pragma unroll
    for (int g = 0; g < 8; ++g) r2 += racc[g][t];
    out[(long)b * D_SZ + t] = r2 * inv;
}

// ================= fallback fused kernel (R5 structure) for small ws =================
__device__ __forceinline__ void gather_half_f(const int* __restrict__ idxp,
                                              const float* __restrict__ table,
                                              bf16* __restrict__ buf, int l0, int t) {
#pragma unroll
    for (int it = 0; it < 6; ++it) {
        int g = it * 256 + t;
        int r = g >> 5, c = g & 31;
        int l = l0 + r;
        int li = l < L_SZ ? l : (L_SZ - 1);
        long row = idxp[li];
        const float* f = table + row * D_SZ + c * 8;
        f32x4 a = *(const f32x4*)f;
        f32x4 b2 = *(const f32x4*)(f + 4);
        bf16x8 v;
        v[0] = (bf16)a[0]; v[1] = (bf16)a[1]; v[2] = (bf16)a[2]; v[3] = (bf16)a[3];
        v[4] = (bf16)b2[0]; v[5] = (bf16)b2[1]; v[6] = (bf16)b2[2]; v[7] = (bf16)b2[3];
        *(bf16x8*)(buf + r * AST + c * 8) = v;
    }
}

__launch_bounds__(256, 3)
__global__ void ua_fused(const int* __restrict__ nodes, const int* __restrict__ hua,
                         const int* __restrict__ hr, const float* __restrict__ u2e,
                         const float* __restrict__ attr, const float* __restrict__ r2e,
                         const bf16* __restrict__ wf1, const bf16* __restrict__ wf2,
                         const bf16* __restrict__ wfa1, const bf16* __restrict__ wfa2,
                         const float* __restrict__ b1w, const float* __restrict__ b2w,
                         const float* __restrict__ att1w, const float* __restrict__ a1b,
                         const float* __restrict__ a2b, const float* __restrict__ att3w,
                         const float* __restrict__ a3bp, float* __restrict__ out) {
    __shared__ __align__(16) bf16 abuf[48 * AST];
    __shared__ __align__(16) bf16 obuf[48 * AST];
    __shared__ float h1pre[D_SZ];
    __shared__ float scratch[288];
    const int b = blockIdx.x, t = threadIdx.x;
    const int wave = t >> 6, lane = t & 63, l16 = t & 15, quad = (t & 63) >> 4;
    {
        int node = nodes[b];
        scratch[t] = u2e[(long)node * D_SZ + t];
        __syncthreads();
        float a = a1b[t];
        const float* wr = att1w + (long)t * 512 + 256;
#pragma unroll
        for (int k = 0; k < 256; k += 4) {
            f32x4 wv = *(const f32x4*)(wr + k);
            a += scratch[k] * wv[0] + scratch[k + 1] * wv[1] +
                 scratch[k + 2] * wv[2] + scratch[k + 3] * wv[3];
        }
        h1pre[t] = a;
        __syncthreads();
    }
    float bias1[4], bias2[4], bias3[4], bias4[4], a3[4];
#pragma unroll
    for (int nt = 0; nt < 4; ++nt) {
        int col = (wave * 4 + nt) * 16 + l16;
        bias1[nt] = b1w[col]; bias2[nt] = b2w[col]; bias3[nt] = h1pre[col];
        bias4[nt] = a2b[col]; a3[nt] = att3w[col];
    }
    const float a3bias = a3bp[0];
    const int* huab = hua + (long)b * L_SZ;
    const int* hrb = hr + (long)b * L_SZ;
    float accv = 0.f, srun = 0.f, mrun = -INFINITY;
    float* score_part = scratch;
    float* score_row = scratch + 192;
    float* wrow = scratch + 240;
    auto st3 = [&](bf16* buf, f32x4 (&acc)[3][4], const float* bias) {
#pragma unroll
        for (int mt = 0; mt < 3; ++mt)
#pragma unroll
            for (int nt = 0; nt < 4; ++nt) {
                int col = (wave * 4 + nt) * 16 + l16;
#pragma unroll
                for (int r = 0; r < 4; ++r) {
                    float v = acc[mt][nt][r] + bias[nt];
                    v = v > 0.f ? v : 0.f;
                    buf[(mt * 16 + quad * 4 + r) * AST + col] = (bf16)v;
                }
            }
    };
    for (int tile = 0; tile < 5; ++tile) {
        const int l0 = tile * 48;
        f32x4 acc[3][4];
        zero_t<3>(acc);
        gather_half_f(huab, attr, abuf, l0, t);
        __syncthreads();
        gemm_t<3, 16>(abuf, wf1, 0, wave, lane, l16, quad, acc);
        __syncthreads();
        gather_half_f(hrb, r2e, abuf, l0, t);
        __syncthreads();
        gemm_t<3, 16>(abuf, wf1, 8, wave, lane, l16, quad, acc);
        __syncthreads();
        st3(abuf, acc, bias1);
        __syncthreads();
        zero_t<3>(acc);
        gemm_t<3, 8>(abuf, wf2, 0, wave, lane, l16, quad, acc);
        st3(obuf, acc, bias2);
        __syncthreads();
        zero_t<3>(acc);
        gemm_t<3, 8>(obuf, wfa1, 0, wave, lane, l16, quad, acc);
        st3(abuf, acc, bias3);
        __syncthreads();
        zero_t<3>(acc);
        gemm_t<3, 8>(abuf, wfa2, 0, wave, lane, l16, quad, acc);
        float p[3][4];
#pragma unroll
        for (int mt = 0; mt < 3; ++mt)
#pragma unroll
            for (int r = 0; r < 4; ++r) {
                float s = 0.f;
#pragma unroll
                for (int nt = 0; nt < 4; ++nt) {
                    float h = acc[mt][nt][r] + bias4[nt];
                    h = h > 0.f ? h : 0.f;
                    s += h * a3[nt];
                }
                p[mt][r] = s;
            }
#pragma unroll
        for (int off = 1; off < 16; off <<= 1)
#pragma unroll
            for (int mt = 0; mt < 3; ++mt)
#pragma unroll
                for (int r = 0; r < 4; ++r) p[mt][r] += __shfl_xor(p[mt][r], off, 16);
        if (l16 == 0) {
#pragma unroll
            for (int mt = 0; mt < 3; ++mt)
#pragma unroll
                for (int r = 0; r < 4; ++r)
                    score_part[wave * 48 + mt * 16 + quad * 4 + r] = p[mt][r];
        }
        __syncthreads();
        if (t < 48) {
            float s = score_part[t] + score_part[48 + t] + score_part[96 + t] +
                      score_part[144 + t] + a3bias;
            score_row[t] = (l0 + t < L_SZ) ? s : -INFINITY;
        }
        __syncthreads();
        float tm = -INFINITY;
        for (int r = 0; r < 48; ++r) tm = fmaxf(tm, score_row[r]);
        float nm = fmaxf(mrun, tm);
        float factor = __expf(mrun - nm);
        if (t < 48) wrow[t] = __expf(score_row[t] - nm);
        __syncthreads();
        float wsum = 0.f, av = 0.f;
#pragma unroll 8
        for (int r = 0; r < 48; ++r) {
            float w = wrow[r];
            wsum += w;
            av += w * (float)obuf[r * AST + t];
        }
        accv = accv * factor + av;
        srun = srun * factor + wsum;
        mrun = nm;
        __syncthreads();
    }
    out[(long)b * D_SZ + t] = accv / srun;
}

extern "C" void kernel_launch(void* const* d_in, const int* in_sizes, int n_in,
                              void* d_out, int out_size, void* d_ws, size_t ws_size,
                              hipStream_t stream) {
    const int* nodes = (const int*)d_in[0];
    const int* hua = (const int*)d_in[1];
    const int* hr = (const int*)d_in[2];
    // d_in[3] history_uat unused
    const float* u2e = (const float*)d_in[4];
    const float* attr = (const float*)d_in[5];
    const float* r2e = (const float*)d_in[6];
    const float* w1 = (const float*)d_in[7];
    const float* b1 = (const float*)d_in[8];
    const float* w2 = (const float*)d_in[9];
    const float* b2 = (const float*)d_in[10];
    const float* a1w = (const float*)d_in[11];
    const float* a1b = (const float*)d_in[12];
    const float* a2w = (const float*)d_in[13];
    const float* a2b = (const float*)d_in[14];
    const float* a3w = (const float*)d_in[15];
    const float* a3b = (const float*)d_in[16];
    char* ws = (char*)d_ws;
    bf16* wf_w2 = (bf16*)(ws + WS_W2F);
    bf16* wf_a1l = (bf16*)(ws + WS_A1L);
    bf16* wf_a1h = (bf16*)(ws + WS_A1H);
    bf16* wf_a2f = (bf16*)(ws + WS_A2F);
    bf16* wf_w1a = (bf16*)(ws + WS_W1A);
    bf16* wf_w1 = (bf16*)(ws + WS_W1F);

    if (ws_size >= (size_t)WS_NEED_NEW) {
        float* Rg = (float*)(ws + WS_R);
        float* h1p = (float*)(ws + WS_H1P);
        float* scores = (float*)(ws + WS_SCR);
        bf16* obuf = (bf16*)(ws + WS_O);
        bf16* Pt = (bf16*)(ws + WS_P);
        swizzle_all<<<161, 256, 0, stream>>>(w2, a1w, a2w, w1,
                                             wf_w2, wf_a1l, wf_a2f, wf_a1h, wf_w1a,
                                             r2e, b1, Rg);
        kpre_k0<<<NPB64 + NK0, 256, 0, stream>>>(attr, wf_w1a, Pt,
                                                 nodes, u2e, wf_a1h, a1b, h1p);
        k1f_fused<<<NROWS / MB2, 256, 0, stream>>>(hua, hr, Pt, Rg, wf_w2, wf_a1l,
                                                   wf_a2f, h1p, b2, a2b, a3w,
                                                   obuf, scores);
        k5_reduce<<<2048, 256, 0, stream>>>(scores, obuf, (float*)d_out);
    } else if (ws_size >= (size_t)WS_NEED_OLD) {
        float* h1p = (float*)(ws + WS_H1P);
        float* scores = (float*)(ws + WS_SCR);
        bf16* obuf = (bf16*)(ws + WS_O);
        swizzle_kernel<<<32, 256, 0, stream>>>(w2, wf_w2, 8, 256, 0, 8192);
        swizzle_kernel<<<32, 256, 0, stream>>>(a1w, wf_a1l, 8, 512, 0, 8192);
        swizzle_kernel<<<32, 256, 0, stream>>>(a2w, wf_a2f, 8, 256, 0, 8192);
        swizzle_kernel<<<64, 256, 0, stream>>>(w1, wf_w1, 16, 512, 0, 16384);
        swizzle_kernel<<<32, 256, 0, stream>>>(a1w, wf_a1h, 8, 512, 256, 8192);
        k0_h1pre<<<2048 / MB, 256, 0, stream>>>(nodes, u2e, wf_a1h, a1b, h1p);
        k1_gemm12<<<NROWS / MB, 256, 0, stream>>>(hua, hr, attr, r2e, wf_w1, wf_w2,
                                                  b1, b2, obuf);
        k2_gemm34<<<NROWS / MB, 256, 0, stream>>>(obuf, wf_a1l, wf_a2f, h1p, a2b,
                                                  a3w, scores);
        k5_reduce<<<2048, 256, 0, stream>>>(scores, obuf, (float*)d_out);
    } else {
        swizzle_kernel<<<32, 256, 0, stream>>>(w2, wf_w2, 8, 256, 0, 8192);
        swizzle_kernel<<<32, 256, 0, stream>>>(a1w, wf_a1l, 8, 512, 0, 8192);
        swizzle_kernel<<<32, 256, 0, stream>>>(a2w, wf_a2f, 8, 256, 0, 8192);
        swizzle_kernel<<<64, 256, 0, stream>>>(w1, wf_w1, 16, 512, 0, 16384);
        ua_fused<<<2048, 256, 0, stream>>>(nodes, hua, hr, u2e, attr, r2e,
                                           wf_w1, wf_w2, wf_a1l, wf_a2f,
                                           b1, b2, a1w, a1b, a2b, a3w, a3b,
                                           (float*)d_out);
    }
}